// Round 1
// baseline (1601.849 us; speedup 1.0000x reference)
//
#include <hip/hip_runtime.h>
#include <hip/hip_bf16.h>

#define T_TOK 1024
#define H_DIM 2048
#define E_NUM 32
#define I_DIM 768
#define N2I   1536

typedef __attribute__((ext_vector_type(8))) __bf16 bf16x8;
typedef __attribute__((ext_vector_type(4))) float  f32x4;

union P8 { short s[8]; uint4 v; };

__device__ __forceinline__ short f2bf(float f) {
  union { float f; unsigned u; } a; a.f = f;
  unsigned u = a.u;
  u += 0x7FFFu + ((u >> 16) & 1u);   // RNE to bf16
  return (short)(u >> 16);
}

// ---------------- routing ----------------
__global__ void zero_cnt_kernel(int* cnt) {
  if (threadIdx.x < E_NUM) cnt[threadIdx.x] = 0;
}

__global__ void route_kernel(const float* __restrict__ X, const float* __restrict__ GW,
                             const float* __restrict__ gbias,
                             int* __restrict__ cnt, int* __restrict__ toks,
                             float* __restrict__ tokw) {
  const int t = blockIdx.x;
  const int tid = threadIdx.x;
  __shared__ float xs[H_DIM];
  const float4* xg = (const float4*)(X + (long)t * H_DIM);
  float4* xl = (float4*)xs;
  for (int i = tid; i < H_DIM / 4; i += 256) xl[i] = xg[i];
  __syncthreads();
  const int e = tid >> 3, l = tid & 7;
  const float* w = GW + (long)e * H_DIM;
  float p = 0.f;
  for (int h = l; h < H_DIM; h += 8) p += xs[h] * w[h];
  p += __shfl_xor(p, 4);
  p += __shfl_xor(p, 2);
  p += __shfl_xor(p, 1);
  __shared__ float lg[E_NUM];
  if (l == 0) lg[e] = p;
  __syncthreads();
  if (tid == 0) {
    float su[E_NUM], sc[E_NUM];
    for (int i = 0; i < E_NUM; ++i) {
      float s = 1.f / (1.f + __expf(-lg[i]));
      su[i] = s; sc[i] = s + gbias[i];
    }
    float gs[4];
    for (int g = 0; g < 4; ++g) {
      float m1 = -1e30f, m2 = -1e30f;
      for (int j = 0; j < 8; ++j) {
        float v = sc[g * 8 + j];
        if (v > m1) { m2 = m1; m1 = v; } else if (v > m2) m2 = v;
      }
      gs[g] = m1 + m2;
    }
    int g1 = 0;
    for (int g = 1; g < 4; ++g) if (gs[g] > gs[g1]) g1 = g;
    int g2 = -1;
    for (int g = 0; g < 4; ++g) { if (g == g1) continue; if (g2 < 0 || gs[g] > gs[g2]) g2 = g; }
    bool mask[E_NUM], taken[E_NUM];
    for (int i = 0; i < E_NUM; ++i) {
      int g = i >> 3;
      mask[i] = (g == g1) || (g == g2);
      taken[i] = false;
    }
    int ids[8]; float wsum = 0.f;
    for (int k = 0; k < 8; ++k) {
      int best = -1;
      for (int i = 0; i < E_NUM; ++i) {
        if (!mask[i] || taken[i]) continue;
        if (best < 0 || sc[i] > sc[best]) best = i;
      }
      taken[best] = true; ids[k] = best; wsum += su[best];
    }
    float inv = 2.5f / wsum;   // fold ROUTED_SCALING into per-row weight
    for (int k = 0; k < 8; ++k) {
      int ei = ids[k];
      int pos = atomicAdd(&cnt[ei], 1);
      toks[ei * T_TOK + pos] = t;
      tokw[ei * T_TOK + pos] = su[ei] * inv;
    }
  }
}

__global__ void offs_kernel(const int* __restrict__ cnt, int* __restrict__ offs) {
  if (threadIdx.x == 0) {
    int run = 0;
    for (int e = 0; e < E_NUM; ++e) { offs[e] = run; run += cnt[e]; }
    offs[E_NUM] = run;
  }
}

// ---------------- fused gate_up + SiLU GEMM ----------------
// BM=128, BN=64 (computed for both gate and up halves), BK=32, 4 waves (2x2),
// each wave 64x32, mfma_f32_16x16x32_bf16.
template <bool ROUTED>
__global__ __launch_bounds__(256)
void gateup_kernel(const float* __restrict__ X, const float* __restrict__ W,
                   const int* __restrict__ cnt, const int* __restrict__ offs,
                   const int* __restrict__ toks, unsigned short* __restrict__ act) {
  const int mt = blockIdx.x, nb = blockIdx.y, e = ROUTED ? blockIdx.z : 0;
  int count, rowbase = 0;
  const int* tl = nullptr;
  if (ROUTED) {
    count = cnt[e];
    if (mt * 128 >= count) return;
    rowbase = offs[e];
    tl = toks + e * T_TOK;
  } else {
    count = T_TOK;
  }
  const float* Wb = ROUTED ? (W + (long)e * H_DIM * N2I) : W;
  const int m0 = mt * 128, n0 = nb * 64;
  __shared__ short As[128 * 40];      // padded stride 40 bf16 (80B = 20 banks)
  __shared__ short Bs[2][64 * 40];    // [gate/up][n][k]
  const int tid = threadIdx.x;
  const int arow = tid >> 1, ahalf = tid & 1;
  const bool avalid = (m0 + arow) < count;
  long agrow = 0;
  if (avalid) agrow = ROUTED ? (long)tl[m0 + arow] : (long)(m0 + arow);
  const float* xp = X + agrow * H_DIM + ahalf * 16;
  const int bn = tid & 63, bkg = tid >> 6;
  const int lane = tid & 63, wv = tid >> 6;
  const int wm = (wv >> 1) * 64, wn = (wv & 1) * 32;
  const int fm = lane & 15, fq = lane >> 4;
  f32x4 accg[4][2] = {};
  f32x4 accu[4][2] = {};

  for (int k0 = 0; k0 < H_DIM; k0 += 32) {
    // ---- stage A (fp32 -> bf16) ----
    P8 pa0, pa1;
    if (avalid) {
      const float4* p = (const float4*)(xp + k0);
      float4 v0 = p[0], v1 = p[1], v2 = p[2], v3 = p[3];
      pa0.s[0] = f2bf(v0.x); pa0.s[1] = f2bf(v0.y); pa0.s[2] = f2bf(v0.z); pa0.s[3] = f2bf(v0.w);
      pa0.s[4] = f2bf(v1.x); pa0.s[5] = f2bf(v1.y); pa0.s[6] = f2bf(v1.z); pa0.s[7] = f2bf(v1.w);
      pa1.s[0] = f2bf(v2.x); pa1.s[1] = f2bf(v2.y); pa1.s[2] = f2bf(v2.z); pa1.s[3] = f2bf(v2.w);
      pa1.s[4] = f2bf(v3.x); pa1.s[5] = f2bf(v3.y); pa1.s[6] = f2bf(v3.z); pa1.s[7] = f2bf(v3.w);
    } else {
      pa0.v = make_uint4(0, 0, 0, 0);
      pa1.v = make_uint4(0, 0, 0, 0);
    }
    *(uint4*)&As[arow * 40 + ahalf * 16]     = pa0.v;
    *(uint4*)&As[arow * 40 + ahalf * 16 + 8] = pa1.v;
    // ---- stage B transposed: lane-per-column loads, pack 8 k's ----
    #pragma unroll
    for (int h = 0; h < 2; ++h) {
      const float* wp = Wb + (long)(k0 + bkg * 8) * N2I + h * I_DIM + n0 + bn;
      P8 pb;
      #pragma unroll
      for (int j = 0; j < 8; ++j) pb.s[j] = f2bf(wp[(long)j * N2I]);
      *(uint4*)&Bs[h][bn * 40 + bkg * 8] = pb.v;
    }
    __syncthreads();
    bf16x8 af[4];
    #pragma unroll
    for (int mi = 0; mi < 4; ++mi)
      af[mi] = *(const bf16x8*)&As[(wm + mi * 16 + fm) * 40 + fq * 8];
    bf16x8 bfr[2][2];
    #pragma unroll
    for (int h = 0; h < 2; ++h)
      #pragma unroll
      for (int ni = 0; ni < 2; ++ni)
        bfr[h][ni] = *(const bf16x8*)&Bs[h][(wn + ni * 16 + fm) * 40 + fq * 8];
    #pragma unroll
    for (int mi = 0; mi < 4; ++mi)
      #pragma unroll
      for (int ni = 0; ni < 2; ++ni) {
        accg[mi][ni] = __builtin_amdgcn_mfma_f32_16x16x32_bf16(af[mi], bfr[0][ni], accg[mi][ni], 0, 0, 0);
        accu[mi][ni] = __builtin_amdgcn_mfma_f32_16x16x32_bf16(af[mi], bfr[1][ni], accu[mi][ni], 0, 0, 0);
      }
    __syncthreads();
  }
  // ---- epilogue: act = silu(g) * u, store bf16 ----
  #pragma unroll
  for (int mi = 0; mi < 4; ++mi)
    #pragma unroll
    for (int ni = 0; ni < 2; ++ni)
      #pragma unroll
      for (int r = 0; r < 4; ++r) {
        int lr = wm + mi * 16 + fq * 4 + r;
        int gr = m0 + lr;
        if (gr < count) {
          int lc = wn + ni * 16 + fm;
          float g = accg[mi][ni][r], u = accu[mi][ni][r];
          float a = g / (1.f + __expf(-g)) * u;
          act[(long)(rowbase + gr) * I_DIM + n0 + lc] = (unsigned short)f2bf(a);
        }
      }
}

// ---------------- down GEMM ----------------
// BM=128, BN=64, BK=32. Shared: direct store. Routed: atomicAdd(out, v*w).
template <bool ROUTED>
__global__ __launch_bounds__(256)
void down_kernel(const unsigned short* __restrict__ act, const float* __restrict__ W,
                 const int* __restrict__ cnt, const int* __restrict__ offs,
                 const int* __restrict__ toks, const float* __restrict__ tokw,
                 float* __restrict__ out) {
  const int mt = blockIdx.x, nb = blockIdx.y, e = ROUTED ? blockIdx.z : 0;
  int count, rowbase = 0;
  if (ROUTED) {
    count = cnt[e];
    if (mt * 128 >= count) return;
    rowbase = offs[e];
  } else {
    count = T_TOK;
  }
  const float* Wb = ROUTED ? (W + (long)e * I_DIM * H_DIM) : W;
  const int m0 = mt * 128, n0 = nb * 64;
  __shared__ short As[128 * 40];
  __shared__ short Bs[64 * 40];
  const int tid = threadIdx.x;
  const int arow = tid >> 1, ahalf = tid & 1;
  const bool avalid = (m0 + arow) < count;
  const unsigned short* ap = act + (long)(rowbase + m0 + arow) * I_DIM + ahalf * 16;
  const int bn = tid & 63, bkg = tid >> 6;
  const int lane = tid & 63, wv = tid >> 6;
  const int wm = (wv >> 1) * 64, wn = (wv & 1) * 32;
  const int fm = lane & 15, fq = lane >> 4;
  f32x4 acc[4][2] = {};

  for (int k0 = 0; k0 < I_DIM; k0 += 32) {
    uint4 a0 = make_uint4(0, 0, 0, 0), a1 = make_uint4(0, 0, 0, 0);
    if (avalid) {
      const uint4* p = (const uint4*)(ap + k0);
      a0 = p[0]; a1 = p[1];
    }
    *(uint4*)&As[arow * 40 + ahalf * 16]     = a0;
    *(uint4*)&As[arow * 40 + ahalf * 16 + 8] = a1;
    const float* wp = Wb + (long)(k0 + bkg * 8) * H_DIM + n0 + bn;
    P8 pb;
    #pragma unroll
    for (int j = 0; j < 8; ++j) pb.s[j] = f2bf(wp[(long)j * H_DIM]);
    *(uint4*)&Bs[bn * 40 + bkg * 8] = pb.v;
    __syncthreads();
    bf16x8 af[4];
    #pragma unroll
    for (int mi = 0; mi < 4; ++mi)
      af[mi] = *(const bf16x8*)&As[(wm + mi * 16 + fm) * 40 + fq * 8];
    bf16x8 bfr[2];
    #pragma unroll
    for (int ni = 0; ni < 2; ++ni)
      bfr[ni] = *(const bf16x8*)&Bs[(wn + ni * 16 + fm) * 40 + fq * 8];
    #pragma unroll
    for (int mi = 0; mi < 4; ++mi)
      #pragma unroll
      for (int ni = 0; ni < 2; ++ni)
        acc[mi][ni] = __builtin_amdgcn_mfma_f32_16x16x32_bf16(af[mi], bfr[ni], acc[mi][ni], 0, 0, 0);
    __syncthreads();
  }
  #pragma unroll
  for (int mi = 0; mi < 4; ++mi)
    #pragma unroll
    for (int ni = 0; ni < 2; ++ni)
      #pragma unroll
      for (int r = 0; r < 4; ++r) {
        int lr = wm + mi * 16 + fq * 4 + r;
        int gr = m0 + lr;
        if (gr < count) {
          int lc = wn + ni * 16 + fm;
          float v = acc[mi][ni][r];
          if (ROUTED) {
            int t = toks[e * T_TOK + gr];
            float wgt = tokw[e * T_TOK + gr];
            atomicAdd(&out[(long)t * H_DIM + n0 + lc], v * wgt);
          } else {
            out[(long)gr * H_DIM + n0 + lc] = v;
          }
        }
      }
}

// ---------------- launch ----------------
extern "C" void kernel_launch(void* const* d_in, const int* in_sizes, int n_in,
                              void* d_out, int out_size, void* d_ws, size_t ws_size,
                              hipStream_t stream) {
  const float* X   = (const float*)d_in[0];
  const float* GW  = (const float*)d_in[1];
  const float* GB  = (const float*)d_in[2];
  const float* WGU = (const float*)d_in[3];
  const float* WD  = (const float*)d_in[4];
  const float* SGU = (const float*)d_in[5];
  const float* SD  = (const float*)d_in[6];
  float* out = (float*)d_out;
  char* ws = (char*)d_ws;

  int*   cnt  = (int*)(ws + 0);
  int*   offs = (int*)(ws + 256);
  int*   toks = (int*)(ws + 1024);                         // E*T ints = 128 KB
  float* tokw = (float*)(ws + 1024 + 131072);              // E*T floats = 128 KB
  unsigned short* act_r = (unsigned short*)(ws + 263168);  // 8192*768 bf16 = 12.6 MB
  unsigned short* act_s = (unsigned short*)(ws + 263168 + 12582912); // 1024*768 bf16

  zero_cnt_kernel<<<1, 64, 0, stream>>>(cnt);
  route_kernel<<<T_TOK, 256, 0, stream>>>(X, GW, GB, cnt, toks, tokw);
  offs_kernel<<<1, 64, 0, stream>>>(cnt, offs);
  // shared expert
  gateup_kernel<false><<<dim3(8, 12, 1), 256, 0, stream>>>(X, SGU, nullptr, nullptr, nullptr, act_s);
  // routed experts
  gateup_kernel<true><<<dim3(8, 12, E_NUM), 256, 0, stream>>>(X, WGU, cnt, offs, toks, act_r);
  // shared down writes d_out fully, then routed down accumulates on top
  down_kernel<false><<<dim3(8, 32, 1), 256, 0, stream>>>(act_s, SD, nullptr, nullptr, nullptr, nullptr, out);
  down_kernel<true><<<dim3(8, 32, E_NUM), 256, 0, stream>>>(act_r, WD, cnt, offs, toks, tokw, out);
}

// Round 2
// 1516.970 us; speedup vs baseline: 1.0560x; 1.0560x over previous
//
#include <hip/hip_runtime.h>
#include <hip/hip_bf16.h>

#define T_TOK 1024
#define H_DIM 2048
#define E_NUM 32
#define I_DIM 768
#define N2I   1536
#define SK    36   // LDS row stride in shorts (BK=32 + 4 pad; 72B row: b64 reads conflict-free)

typedef __attribute__((ext_vector_type(8))) __bf16 bf16x8;
typedef __attribute__((ext_vector_type(4))) float  f32x4;

__device__ __forceinline__ short f2bf(float f) {
  union { float f; unsigned u; } a; a.f = f;
  unsigned u = a.u;
  u += 0x7FFFu + ((u >> 16) & 1u);   // RNE to bf16
  return (short)(u >> 16);
}

__device__ __forceinline__ unsigned pkbf(float lo, float hi) {
  return (unsigned)(unsigned short)f2bf(lo) | ((unsigned)(unsigned short)f2bf(hi) << 16);
}

union FR { uint2 d[2]; bf16x8 v; };

// ---------------- routing ----------------
__global__ void zero_cnt_kernel(int* cnt) {
  if (threadIdx.x < E_NUM) cnt[threadIdx.x] = 0;
}

__global__ void route_kernel(const float* __restrict__ X, const float* __restrict__ GW,
                             const float* __restrict__ gbias,
                             int* __restrict__ cnt, int* __restrict__ toks,
                             float* __restrict__ tokw) {
  const int t = blockIdx.x;
  const int tid = threadIdx.x;
  __shared__ float xs[H_DIM];
  const float4* xg = (const float4*)(X + (long)t * H_DIM);
  float4* xl = (float4*)xs;
  for (int i = tid; i < H_DIM / 4; i += 256) xl[i] = xg[i];
  __syncthreads();
  const int e = tid >> 3, l = tid & 7;
  const float* w = GW + (long)e * H_DIM;
  float p = 0.f;
  for (int h = l; h < H_DIM; h += 8) p += xs[h] * w[h];
  p += __shfl_xor(p, 4);
  p += __shfl_xor(p, 2);
  p += __shfl_xor(p, 1);
  __shared__ float lg[E_NUM];
  if (l == 0) lg[e] = p;
  __syncthreads();
  if (tid == 0) {
    float su[E_NUM], sc[E_NUM];
    for (int i = 0; i < E_NUM; ++i) {
      float s = 1.f / (1.f + __expf(-lg[i]));
      su[i] = s; sc[i] = s + gbias[i];
    }
    float gs[4];
    for (int g = 0; g < 4; ++g) {
      float m1 = -1e30f, m2 = -1e30f;
      for (int j = 0; j < 8; ++j) {
        float v = sc[g * 8 + j];
        if (v > m1) { m2 = m1; m1 = v; } else if (v > m2) m2 = v;
      }
      gs[g] = m1 + m2;
    }
    int g1 = 0;
    for (int g = 1; g < 4; ++g) if (gs[g] > gs[g1]) g1 = g;
    int g2 = -1;
    for (int g = 0; g < 4; ++g) { if (g == g1) continue; if (g2 < 0 || gs[g] > gs[g2]) g2 = g; }
    bool mask[E_NUM], taken[E_NUM];
    for (int i = 0; i < E_NUM; ++i) {
      int g = i >> 3;
      mask[i] = (g == g1) || (g == g2);
      taken[i] = false;
    }
    int ids[8]; float wsum = 0.f;
    for (int k = 0; k < 8; ++k) {
      int best = -1;
      for (int i = 0; i < E_NUM; ++i) {
        if (!mask[i] || taken[i]) continue;
        if (best < 0 || sc[i] > sc[best]) best = i;
      }
      taken[best] = true; ids[k] = best; wsum += su[best];
    }
    float inv = 2.5f / wsum;
    for (int k = 0; k < 8; ++k) {
      int ei = ids[k];
      int pos = atomicAdd(&cnt[ei], 1);
      toks[ei * T_TOK + pos] = t;
      tokw[ei * T_TOK + pos] = su[ei] * inv;
    }
  }
}

__global__ void offs_kernel(const int* __restrict__ cnt, int* __restrict__ offs) {
  if (threadIdx.x == 0) {
    int run = 0;
    for (int e = 0; e < E_NUM; ++e) { offs[e] = run; run += cnt[e]; }
    offs[E_NUM] = run;
  }
}

// ---------------- X -> bf16 ----------------
__global__ void xconv_kernel(const float* __restrict__ X, unsigned short* __restrict__ Xb) {
  int i = (blockIdx.x * 256 + threadIdx.x) * 4;
  float4 v = *(const float4*)(X + i);
  uint2 o;
  o.x = pkbf(v.x, v.y);
  o.y = pkbf(v.z, v.w);
  *(uint2*)(Xb + i) = o;
}

// ---------------- fused gate_up + SiLU GEMM ----------------
// BM=128, BN=64 (both gate and up halves), BK=32, 4 waves (2x2).
// A: bf16 k-contig, B: fp32 [k][n] loaded coalesced, transposed on LDS write.
template <bool ROUTED>
__global__ __launch_bounds__(256)
void gateup_kernel(const unsigned short* __restrict__ Xb, const float* __restrict__ W,
                   const int* __restrict__ cnt, const int* __restrict__ offs,
                   const int* __restrict__ toks, unsigned short* __restrict__ act) {
  const int mt = blockIdx.x, nb = blockIdx.y, e = ROUTED ? blockIdx.z : 0;
  int count, rowbase = 0;
  const int* tl = nullptr;
  if (ROUTED) {
    count = cnt[e];
    if (mt * 128 >= count) return;
    rowbase = offs[e];
    tl = toks + e * T_TOK;
  } else {
    count = T_TOK;
  }
  const float* Wb = ROUTED ? (W + (long)e * H_DIM * N2I) : W;
  const int m0 = mt * 128, n0 = nb * 64;
  __shared__ short As[128 * SK];
  __shared__ short Bs[2][64 * SK];
  const int tid = threadIdx.x;
  // A staging: 2 threads per row, 16 bf16 each
  const int arow = tid >> 1, ahalf = tid & 1;
  const bool avalid = (m0 + arow) < count;
  long agrow = 0;
  if (avalid) agrow = ROUTED ? (long)tl[m0 + arow] : (long)(m0 + arow);
  const unsigned short* xp = Xb + agrow * H_DIM + ahalf * 16;
  const int abase = arow * SK + ahalf * 16;
  // B staging: fm4 = 4 consecutive n, kk2 = k-pair, hh = gate/up half
  const int fm4 = (tid & 15) * 4;
  const int kk2 = (tid >> 4) & 7;
  const int hh  = tid >> 7;
  const float* wp0 = Wb + hh * I_DIM + n0 + fm4;
  // MFMA frag ids
  const int lane = tid & 63, wv = tid >> 6;
  const int wm = (wv >> 1) * 64, wn = (wv & 1) * 32;
  const int fm = lane & 15, fq = lane >> 4;
  f32x4 accg[4][2] = {};
  f32x4 accu[4][2] = {};

  for (int k0 = 0; k0 < H_DIM; k0 += 32) {
    // ---- stage A (bf16, straight copy) ----
    uint4 a0 = make_uint4(0, 0, 0, 0), a1 = make_uint4(0, 0, 0, 0);
    if (avalid) {
      const uint4* p = (const uint4*)(xp + k0);
      a0 = p[0]; a1 = p[1];
    }
    *(uint2*)&As[abase +  0] = make_uint2(a0.x, a0.y);
    *(uint2*)&As[abase +  4] = make_uint2(a0.z, a0.w);
    *(uint2*)&As[abase +  8] = make_uint2(a1.x, a1.y);
    *(uint2*)&As[abase + 12] = make_uint2(a1.z, a1.w);
    // ---- stage B: coalesced fp32 dwordx4, cvt, transpose on LDS write ----
    #pragma unroll
    for (int p = 0; p < 2; ++p) {
      const int krow = k0 + p * 16 + kk2 * 2;
      float4 w0 = *(const float4*)(wp0 + (long)krow * N2I);
      float4 w1 = *(const float4*)(wp0 + (long)(krow + 1) * N2I);
      const int bb = p * 16 + kk2 * 2;
      short* bs = &Bs[hh][0];
      *(unsigned*)&bs[(fm4 + 0) * SK + bb] = pkbf(w0.x, w1.x);
      *(unsigned*)&bs[(fm4 + 1) * SK + bb] = pkbf(w0.y, w1.y);
      *(unsigned*)&bs[(fm4 + 2) * SK + bb] = pkbf(w0.z, w1.z);
      *(unsigned*)&bs[(fm4 + 3) * SK + bb] = pkbf(w0.w, w1.w);
    }
    __syncthreads();
    bf16x8 af[4];
    #pragma unroll
    for (int mi = 0; mi < 4; ++mi) {
      FR f;
      const int ra = (wm + mi * 16 + fm) * SK + fq * 8;
      f.d[0] = *(const uint2*)&As[ra];
      f.d[1] = *(const uint2*)&As[ra + 4];
      af[mi] = f.v;
    }
    bf16x8 bfr[2][2];
    #pragma unroll
    for (int h = 0; h < 2; ++h)
      #pragma unroll
      for (int ni = 0; ni < 2; ++ni) {
        FR f;
        const int rb = (wn + ni * 16 + fm) * SK + fq * 8;
        f.d[0] = *(const uint2*)&Bs[h][rb];
        f.d[1] = *(const uint2*)&Bs[h][rb + 4];
        bfr[h][ni] = f.v;
      }
    #pragma unroll
    for (int mi = 0; mi < 4; ++mi)
      #pragma unroll
      for (int ni = 0; ni < 2; ++ni) {
        accg[mi][ni] = __builtin_amdgcn_mfma_f32_16x16x32_bf16(af[mi], bfr[0][ni], accg[mi][ni], 0, 0, 0);
        accu[mi][ni] = __builtin_amdgcn_mfma_f32_16x16x32_bf16(af[mi], bfr[1][ni], accu[mi][ni], 0, 0, 0);
      }
    __syncthreads();
  }
  // ---- epilogue: act = silu(g) * u, bf16 store ----
  #pragma unroll
  for (int mi = 0; mi < 4; ++mi)
    #pragma unroll
    for (int ni = 0; ni < 2; ++ni)
      #pragma unroll
      for (int r = 0; r < 4; ++r) {
        int lr = wm + mi * 16 + fq * 4 + r;
        int gr = m0 + lr;
        if (gr < count) {
          int lc = wn + ni * 16 + fm;
          float g = accg[mi][ni][r], u = accu[mi][ni][r];
          float a = g / (1.f + __expf(-g)) * u;
          act[(long)(rowbase + gr) * I_DIM + n0 + lc] = (unsigned short)f2bf(a);
        }
      }
}

// ---------------- down GEMM ----------------
// BM=128, BN=64, BK=32. A = bf16 act (contiguous rows), B = fp32 [I][H].
template <bool ROUTED>
__global__ __launch_bounds__(256)
void down_kernel(const unsigned short* __restrict__ act, const float* __restrict__ W,
                 const int* __restrict__ cnt, const int* __restrict__ offs,
                 const int* __restrict__ toks, const float* __restrict__ tokw,
                 float* __restrict__ out) {
  const int mt = blockIdx.x, nb = blockIdx.y, e = ROUTED ? blockIdx.z : 0;
  int count, rowbase = 0;
  if (ROUTED) {
    count = cnt[e];
    if (mt * 128 >= count) return;
    rowbase = offs[e];
  } else {
    count = T_TOK;
  }
  const float* Wb = ROUTED ? (W + (long)e * I_DIM * H_DIM) : W;
  const int m0 = mt * 128, n0 = nb * 64;
  __shared__ short As[128 * SK];
  __shared__ short Bs[64 * SK];
  const int tid = threadIdx.x;
  const int arow = tid >> 1, ahalf = tid & 1;
  const bool avalid = (m0 + arow) < count;
  const unsigned short* ap = act + (long)(rowbase + m0 + arow) * I_DIM + ahalf * 16;
  const int abase = arow * SK + ahalf * 16;
  const int fm4 = (tid & 15) * 4;
  const int kk2 = tid >> 4;           // 0..15 -> covers BK=32 as pairs
  const float* wp0 = Wb + n0 + fm4;
  const int lane = tid & 63, wv = tid >> 6;
  const int wm = (wv >> 1) * 64, wn = (wv & 1) * 32;
  const int fm = lane & 15, fq = lane >> 4;
  f32x4 acc[4][2] = {};

  for (int k0 = 0; k0 < I_DIM; k0 += 32) {
    uint4 a0 = make_uint4(0, 0, 0, 0), a1 = make_uint4(0, 0, 0, 0);
    if (avalid) {
      const uint4* p = (const uint4*)(ap + k0);
      a0 = p[0]; a1 = p[1];
    }
    *(uint2*)&As[abase +  0] = make_uint2(a0.x, a0.y);
    *(uint2*)&As[abase +  4] = make_uint2(a0.z, a0.w);
    *(uint2*)&As[abase +  8] = make_uint2(a1.x, a1.y);
    *(uint2*)&As[abase + 12] = make_uint2(a1.z, a1.w);
    {
      const int krow = k0 + kk2 * 2;
      float4 w0 = *(const float4*)(wp0 + (long)krow * H_DIM);
      float4 w1 = *(const float4*)(wp0 + (long)(krow + 1) * H_DIM);
      const int bb = kk2 * 2;
      *(unsigned*)&Bs[(fm4 + 0) * SK + bb] = pkbf(w0.x, w1.x);
      *(unsigned*)&Bs[(fm4 + 1) * SK + bb] = pkbf(w0.y, w1.y);
      *(unsigned*)&Bs[(fm4 + 2) * SK + bb] = pkbf(w0.z, w1.z);
      *(unsigned*)&Bs[(fm4 + 3) * SK + bb] = pkbf(w0.w, w1.w);
    }
    __syncthreads();
    bf16x8 af[4];
    #pragma unroll
    for (int mi = 0; mi < 4; ++mi) {
      FR f;
      const int ra = (wm + mi * 16 + fm) * SK + fq * 8;
      f.d[0] = *(const uint2*)&As[ra];
      f.d[1] = *(const uint2*)&As[ra + 4];
      af[mi] = f.v;
    }
    bf16x8 bfr[2];
    #pragma unroll
    for (int ni = 0; ni < 2; ++ni) {
      FR f;
      const int rb = (wn + ni * 16 + fm) * SK + fq * 8;
      f.d[0] = *(const uint2*)&Bs[rb];
      f.d[1] = *(const uint2*)&Bs[rb + 4];
      bfr[ni] = f.v;
    }
    #pragma unroll
    for (int mi = 0; mi < 4; ++mi)
      #pragma unroll
      for (int ni = 0; ni < 2; ++ni)
        acc[mi][ni] = __builtin_amdgcn_mfma_f32_16x16x32_bf16(af[mi], bfr[ni], acc[mi][ni], 0, 0, 0);
    __syncthreads();
  }
  #pragma unroll
  for (int mi = 0; mi < 4; ++mi)
    #pragma unroll
    for (int ni = 0; ni < 2; ++ni)
      #pragma unroll
      for (int r = 0; r < 4; ++r) {
        int lr = wm + mi * 16 + fq * 4 + r;
        int gr = m0 + lr;
        if (gr < count) {
          int lc = wn + ni * 16 + fm;
          float v = acc[mi][ni][r];
          if (ROUTED) {
            int t = toks[e * T_TOK + gr];
            float wgt = tokw[e * T_TOK + gr];
            atomicAdd(&out[(long)t * H_DIM + n0 + lc], v * wgt);
          } else {
            out[(long)gr * H_DIM + n0 + lc] = v;
          }
        }
      }
}

// ---------------- launch ----------------
extern "C" void kernel_launch(void* const* d_in, const int* in_sizes, int n_in,
                              void* d_out, int out_size, void* d_ws, size_t ws_size,
                              hipStream_t stream) {
  const float* X   = (const float*)d_in[0];
  const float* GW  = (const float*)d_in[1];
  const float* GB  = (const float*)d_in[2];
  const float* WGU = (const float*)d_in[3];
  const float* WD  = (const float*)d_in[4];
  const float* SGU = (const float*)d_in[5];
  const float* SD  = (const float*)d_in[6];
  float* out = (float*)d_out;
  char* ws = (char*)d_ws;

  int*   cnt  = (int*)(ws + 0);
  int*   offs = (int*)(ws + 256);
  int*   toks = (int*)(ws + 1024);                           // E*T ints = 128 KB
  float* tokw = (float*)(ws + 1024 + 131072);                // E*T floats = 128 KB
  unsigned short* act_r = (unsigned short*)(ws + 263168);    // 8192*768 bf16 = 12.58 MB
  unsigned short* act_s = (unsigned short*)(ws + 263168 + 12582912);      // 1024*768 bf16
  unsigned short* Xb    = (unsigned short*)(ws + 263168 + 12582912 + 1572864); // 1024*2048 bf16

  zero_cnt_kernel<<<1, 64, 0, stream>>>(cnt);
  route_kernel<<<T_TOK, 256, 0, stream>>>(X, GW, GB, cnt, toks, tokw);
  offs_kernel<<<1, 64, 0, stream>>>(cnt, offs);
  xconv_kernel<<<T_TOK * H_DIM / 1024, 256, 0, stream>>>(X, Xb);
  // shared expert
  gateup_kernel<false><<<dim3(8, 12, 1), 256, 0, stream>>>(Xb, SGU, nullptr, nullptr, nullptr, act_s);
  // routed experts
  gateup_kernel<true><<<dim3(8, 12, E_NUM), 256, 0, stream>>>(Xb, WGU, cnt, offs, toks, act_r);
  // shared down writes d_out fully, then routed down accumulates on top
  down_kernel<false><<<dim3(8, 32, 1), 256, 0, stream>>>(act_s, SD, nullptr, nullptr, nullptr, nullptr, out);
  down_kernel<true><<<dim3(8, 32, E_NUM), 256, 0, stream>>>(act_r, WD, cnt, offs, toks, tokw, out);
}